// Round 2
// baseline (5496.383 us; speedup 1.0000x reference)
//
#include <hip/hip_runtime.h>
#include <hip/hip_bf16.h>
#include <cstdint>
#include <cstddef>

// Problem constants (match reference)
#define Hdim 1024
#define Vdim 32000
#define LAYERS 3
#define Bdim 64
#define Tdim 32
#define BT 2048      // B*T
#define G3H 3072     // 3*H

using bf16 = __bf16;
using bf16x8 = __attribute__((ext_vector_type(8))) __bf16;  // one MFMA A/B fragment (4 VGPRs)
using bf16x4 = __attribute__((ext_vector_type(4))) __bf16;
using f32x4  = __attribute__((ext_vector_type(4))) float;

// async global->LDS, 16B per lane. LDS dest is wave-uniform base + lane*16.
typedef const __attribute__((address_space(1))) void* gas1_t;
typedef __attribute__((address_space(3))) void* las3_t;
__device__ __forceinline__ void g2lds16(const void* g, void* l) {
  __builtin_amdgcn_global_load_lds((gas1_t)g, (las3_t)l, 16, 0, 0);
}

// ---------------- fp32 -> bf16 conversion (weights) ----------------
__global__ __launch_bounds__(256) void cvt_f32_bf16(const float* __restrict__ src,
                                                    bf16* __restrict__ dst, int n4) {
  int i = blockIdx.x * 256 + threadIdx.x;
  if (i < n4) {
    f32x4 v = ((const f32x4*)src)[i];
    bf16x4 o;
    o[0] = (bf16)v[0]; o[1] = (bf16)v[1]; o[2] = (bf16)v[2]; o[3] = (bf16)v[3];
    ((bf16x4*)dst)[i] = o;
  }
}

// ---------------- embedding + relu -> bf16 x0 ----------------
__global__ __launch_bounds__(256) void embed_relu(const int* __restrict__ tgt,
                                                  const float* __restrict__ emb,
                                                  bf16* __restrict__ x) {
  int row = blockIdx.x;
  int b = row >> 5, t = row & 31;
  int id = (t == 0) ? 0 : tgt[b * Tdim + t - 1];
  const f32x4* src = (const f32x4*)(emb + (size_t)id * Hdim);
  bf16x4* dst = (bf16x4*)(x + (size_t)row * Hdim);
  f32x4 v = src[threadIdx.x];
  bf16x4 o;
  o[0] = (bf16)fmaxf(v[0], 0.f); o[1] = (bf16)fmaxf(v[1], 0.f);
  o[2] = (bf16)fmaxf(v[2], 0.f); o[3] = (bf16)fmaxf(v[3], 0.f);
  dst[threadIdx.x] = o;
}

// ---------------- hidden-state init: bf16 copy of encoder_hidden[l] + ctr reset ----
__global__ __launch_bounds__(256) void hinit(const float* __restrict__ eh,
                                             bf16* __restrict__ hbf,
                                             unsigned int* __restrict__ ctr) {
  if (blockIdx.x == 0 && threadIdx.x == 0) *ctr = 0u;
  int i = blockIdx.x * 256 + threadIdx.x;   // 64 blocks * 256 * 4 = 65536 floats
  f32x4 v = ((const f32x4*)eh)[i];
  bf16x4 o;
  o[0] = (bf16)v[0]; o[1] = (bf16)v[1]; o[2] = (bf16)v[2]; o[3] = (bf16)v[3];
  ((bf16x4*)hbf)[i] = o;
}

// ---------------- C = A @ B^T (+bias), LDS-staged (m97 structure) ----------------
// A: [M,K] bf16 row-major. Bm: [N,K] bf16 row-major. C: [M,N] fp32.
// Block 128x128 (4 waves, 64x64 each), BK=32, global_load_lds dwordx4 staging.
// XCD-chunked bijective swizzle (T1): each XCD gets a contiguous N-panel slice
// so its L2 holds one B-slice + all of A. Requires nwg % 8 == 0 (holds: 4000, 384).
template <bool BIAS>
__global__ __launch_bounds__(256) void gemm_lds(const bf16* __restrict__ A,
                                                const bf16* __restrict__ Bm,
                                                const float* __restrict__ bias,
                                                float* __restrict__ C,
                                                int M, int N, int K) {
  __shared__ bf16 As[128 * 32];   // 8 KB, row-major [128][32]
  __shared__ bf16 Bs[128 * 32];   // 8 KB

  int wave = threadIdx.x >> 6, lane = threadIdx.x & 63;
  int lane15 = lane & 15, quad = lane >> 4;
  int wr = wave >> 1, wc = wave & 1;

  // ---- XCD-chunked swizzle: HW maps flat%8 -> XCD. Give XCD c the ids
  // [c*per, (c+1)*per) in sweep order (M fast within an N-panel).
  int flat = blockIdx.y * gridDim.x + blockIdx.x;
  int per = (gridDim.x * gridDim.y) >> 3;
  int nid = (flat & 7) * per + (flat >> 3);
  int mt = nid % gridDim.x;
  int nt = nid / gridDim.x;
  int m0 = mt * 128;
  int n0 = nt * 128;

  // staging source pointers: round r covers rows [r*64 + wave*16, +16)
  int srow = wave * 16 + (lane >> 2);       // 0..63
  int scol = (lane & 3) * 8;                // 0,8,16,24
  const bf16* Asrc = A + (size_t)(m0 + srow) * K + scol;
  const bf16* Bsrc = Bm + (size_t)(n0 + srow) * K + scol;
  bf16* AdstW = As + (size_t)wave * 512;    // wave-uniform LDS base (elements)
  bf16* BdstW = Bs + (size_t)wave * 512;

  f32x4 acc[4][4] = {};
  for (int k0 = 0; k0 < K; k0 += 32) {
#pragma unroll
    for (int r = 0; r < 2; r++) {
      g2lds16(Asrc + (size_t)(r * 64) * K + k0, AdstW + r * 2048);
      g2lds16(Bsrc + (size_t)(r * 64) * K + k0, BdstW + r * 2048);
    }
    __syncthreads();   // compiler emits vmcnt(0) drain before s_barrier

    bf16x8 a[4], b[4];
#pragma unroll
    for (int mi = 0; mi < 4; mi++)
      a[mi] = *(const bf16x8*)&As[(wr * 64 + mi * 16 + lane15) * 32 + quad * 8];
#pragma unroll
    for (int ni = 0; ni < 4; ni++)
      b[ni] = *(const bf16x8*)&Bs[(wc * 64 + ni * 16 + lane15) * 32 + quad * 8];
#pragma unroll
    for (int mi = 0; mi < 4; mi++)
#pragma unroll
      for (int ni = 0; ni < 4; ni++)
        acc[mi][ni] = __builtin_amdgcn_mfma_f32_16x16x32_bf16(a[mi], b[ni], acc[mi][ni], 0, 0, 0);
    __syncthreads();
  }

#pragma unroll
  for (int mi = 0; mi < 4; mi++)
#pragma unroll
    for (int ni = 0; ni < 4; ni++) {
      int col = n0 + wc * 64 + ni * 16 + lane15;
      float bv = BIAS ? bias[col] : 0.f;
#pragma unroll
      for (int r = 0; r < 4; r++) {
        int row = m0 + wr * 64 + mi * 16 + quad * 4 + r;
        C[(size_t)row * N + col] = acc[mi][ni][r] + bv;
      }
    }
}

// ---------------- persistent GRU layer: all 32 time steps in one launch ----------
// Grid = 256 blocks x 256 threads = 1 block/CU (co-resident by construction:
// 12 KB LDS, 4 waves). Block (i_tile = bid%64, b_tile = bid/64) owns a 16b x 16i
// output patch; wave w owns K-slice [w*256, w*256+256).
// Whh fragments (3 gates x 8 k-iters = 24 bf16x8 = 96 VGPR) are loaded ONCE and
// reused across all 32 steps. h (fp32) lives in a register per output thread.
// Grid-wide sync between steps: monotone agent-scope atomic counter.
// Race-freedom: reads(t) and writes(t) both precede barrier(t); writes(t+1) go
// to the buffer read at t-1, which every block finished reading before barrier(t).
__global__ __launch_bounds__(256, 1) void gru_layer(
    const bf16* __restrict__ hbf0,    // [B,H] bf16 initial h (from hinit)
    const float* __restrict__ eh,     // [B,H] fp32 initial h (encoder_hidden[l])
    const bf16* __restrict__ Whh,     // [3H,H] bf16
    const float* __restrict__ bhh,    // [3H]
    const float* __restrict__ xp,     // [BT,3H] fp32
    bf16* __restrict__ hbfa,          // ping-pong bf16 h buffers
    bf16* __restrict__ hbfb,
    bf16* __restrict__ y,             // [BT,H] bf16 layer output
    float* __restrict__ finals,       // [B,H] fp32 final h for this layer
    unsigned int* __restrict__ ctr) {
  __shared__ float part[3][4][256];
  int tid = threadIdx.x;
  int wave = tid >> 6, lane = tid & 63;
  int lane15 = lane & 15, quad = lane >> 4;
  int bid = blockIdx.x;
  int i0 = (bid & 63) * 16;     // i-tile (XCD = bid%8 = i-tile%8 -> Whh slice L2-resident)
  int b0 = (bid >> 6) * 16;     // b-tile
  int kbase = wave * 256;

  // ---- preload Whh fragments into registers (reused for all 32 steps)
  const bf16* Wr = Whh + (size_t)(i0 + lane15) * Hdim + kbase + quad * 8;
  const bf16* Wz = Wr + (size_t)Hdim * Hdim;
  const bf16* Wn = Wr + 2 * (size_t)Hdim * Hdim;
  bf16x8 wr_[8], wz_[8], wn_[8];
#pragma unroll
  for (int j = 0; j < 8; j++) {
    wr_[j] = *(const bf16x8*)(Wr + j * 32);
    wz_[j] = *(const bf16x8*)(Wz + j * 32);
    wn_[j] = *(const bf16x8*)(Wn + j * 32);
  }

  // ---- per-output-thread constants
  int b_local = tid >> 4, i_local = tid & 15;
  int i_out = i0 + i_local;
  int b_out = b0 + b_local;
  float bhr = bhh[i_out], bhz = bhh[Hdim + i_out], bhn = bhh[2 * Hdim + i_out];
  size_t hi = (size_t)b_out * Hdim + i_out;
  float hold = eh[hi];                       // fp32 h carried in a register
  const float* xpr = xp + ((size_t)b_out * Tdim) * G3H;

  unsigned int target = 0;
  for (int t = 0; t < Tdim; t++) {
    const bf16* hp = (t & 1) ? hbfb : hbfa;
    bf16*       hn_ = (t & 1) ? hbfa : hbfb;

    // xp loads for this step (independent of h -> issue early)
    float xr = xpr[(size_t)t * G3H + i_out];
    float xz = xpr[(size_t)t * G3H + Hdim + i_out];
    float xn = xpr[(size_t)t * G3H + 2 * Hdim + i_out];

    const bf16* Ap = hp + (size_t)(b0 + lane15) * Hdim + kbase + quad * 8;
    bf16x8 a[8];
#pragma unroll
    for (int j = 0; j < 8; j++) a[j] = *(const bf16x8*)(Ap + j * 32);
    f32x4 ar = {}, az = {}, an = {};
#pragma unroll
    for (int j = 0; j < 8; j++) {
      ar = __builtin_amdgcn_mfma_f32_16x16x32_bf16(a[j], wr_[j], ar, 0, 0, 0);
      az = __builtin_amdgcn_mfma_f32_16x16x32_bf16(a[j], wz_[j], az, 0, 0, 0);
      an = __builtin_amdgcn_mfma_f32_16x16x32_bf16(a[j], wn_[j], an, 0, 0, 0);
    }
    // C/D layout: row(m=b) = quad*4+r, col(n=i) = lane15
#pragma unroll
    for (int r = 0; r < 4; r++) {
      int idx = (quad * 4 + r) * 16 + lane15;
      part[0][wave][idx] = ar[r];
      part[1][wave][idx] = az[r];
      part[2][wave][idx] = an[r];
    }
    __syncthreads();

    float hr = part[0][0][tid] + part[0][1][tid] + part[0][2][tid] + part[0][3][tid] + bhr;
    float hz = part[1][0][tid] + part[1][1][tid] + part[1][2][tid] + part[1][3][tid] + bhz;
    float hnp = part[2][0][tid] + part[2][1][tid] + part[2][2][tid] + part[2][3][tid] + bhn;
    float rg = 1.f / (1.f + __expf(-(xr + hr)));
    float zg = 1.f / (1.f + __expf(-(xz + hz)));
    float ng = tanhf(xn + rg * hnp);
    float hnew = (1.f - zg) * ng + zg * hold;
    hold = hnew;
    hn_[hi] = (bf16)hnew;
    y[((size_t)b_out * Tdim + t) * Hdim + i_out] = (bf16)hnew;

    __syncthreads();          // LDS safe for reuse; also orders before barrier
    __threadfence();          // make h/y stores device-visible before arrival
    target += 256;
    if (tid == 0) {
      __hip_atomic_fetch_add(ctr, 1u, __ATOMIC_RELEASE, __HIP_MEMORY_SCOPE_AGENT);
      while (__hip_atomic_load(ctr, __ATOMIC_RELAXED, __HIP_MEMORY_SCOPE_AGENT) < target)
        __builtin_amdgcn_s_sleep(2);
    }
    __syncthreads();
    __threadfence();          // acquire side: invalidate stale cached h lines
  }
  finals[hi] = hold;
}

// ---------------- in-place log_softmax over V per row (float4) ----------------
__global__ __launch_bounds__(256) void logsoftmax(float* __restrict__ out) {
  __shared__ float sm[256], ss[256];
  int row = blockIdx.x;
  f32x4* x = (f32x4*)(out + (size_t)row * Vdim);
  const int n4 = Vdim / 4;  // 8000
  float m = -1e30f, s = 0.f;
  for (int j = threadIdx.x; j < n4; j += 256) {
    f32x4 v = x[j];
    float vm = fmaxf(fmaxf(v[0], v[1]), fmaxf(v[2], v[3]));
    float nm = fmaxf(m, vm);
    s = s * __expf(m - nm) + __expf(v[0] - nm) + __expf(v[1] - nm)
                           + __expf(v[2] - nm) + __expf(v[3] - nm);
    m = nm;
  }
  sm[threadIdx.x] = m; ss[threadIdx.x] = s;
  __syncthreads();
  for (int off = 128; off; off >>= 1) {
    if (threadIdx.x < off) {
      float m1 = sm[threadIdx.x], s1 = ss[threadIdx.x];
      float m2 = sm[threadIdx.x + off], s2 = ss[threadIdx.x + off];
      float mm = fmaxf(m1, m2);
      sm[threadIdx.x] = mm;
      ss[threadIdx.x] = s1 * __expf(m1 - mm) + s2 * __expf(m2 - mm);
    }
    __syncthreads();
  }
  float lse = sm[0] + logf(ss[0]);
  for (int j = threadIdx.x; j < n4; j += 256) {
    f32x4 v = x[j];
    v[0] -= lse; v[1] -= lse; v[2] -= lse; v[3] -= lse;
    x[j] = v;
  }
}

extern "C" void kernel_launch(void* const* d_in, const int* in_sizes, int n_in,
                              void* d_out, int out_size, void* d_ws, size_t ws_size,
                              hipStream_t stream) {
  const float* enc_hidden = (const float*)d_in[1];
  const int*   target     = (const int*)d_in[2];
  const float* emb        = (const float*)d_in[3];
  const float* W_ih       = (const float*)d_in[4];
  const float* W_hh       = (const float*)d_in[5];
  const float* b_ih       = (const float*)d_in[6];
  const float* b_hh       = (const float*)d_in[7];
  const float* W_out      = (const float*)d_in[8];
  const float* b_out      = (const float*)d_in[9];

  float* out = (float*)d_out;                       // [BT, V] logits/logprobs
  float* finals = out + (size_t)BT * Vdim;          // [L, B, H]

  uint8_t* wsp = (uint8_t*)d_ws;
  auto alloc = [&](size_t bytes) {
    uint8_t* p = wsp;
    wsp += (bytes + 255) & ~(size_t)255;
    return p;
  };
  bf16* wih_bf  = (bf16*)alloc((size_t)LAYERS * G3H * Hdim * 2);
  bf16* whh_bf  = (bf16*)alloc((size_t)LAYERS * G3H * Hdim * 2);
  bf16* wout_bf = (bf16*)alloc((size_t)Vdim * Hdim * 2);
  bf16* xA      = (bf16*)alloc((size_t)BT * Hdim * 2);
  bf16* xB      = (bf16*)alloc((size_t)BT * Hdim * 2);
  float* xp     = (float*)alloc((size_t)BT * G3H * 4);
  bf16* hbfa    = (bf16*)alloc((size_t)Bdim * Hdim * 2);
  bf16* hbfb    = (bf16*)alloc((size_t)Bdim * Hdim * 2);
  unsigned int* ctr = (unsigned int*)alloc(256);

  {
    int n4 = LAYERS * G3H * Hdim / 4;
    cvt_f32_bf16<<<(n4 + 255) / 256, 256, 0, stream>>>(W_ih, wih_bf, n4);
    cvt_f32_bf16<<<(n4 + 255) / 256, 256, 0, stream>>>(W_hh, whh_bf, n4);
    int m4 = Vdim * Hdim / 4;
    cvt_f32_bf16<<<(m4 + 255) / 256, 256, 0, stream>>>(W_out, wout_bf, m4);
  }

  embed_relu<<<BT, 256, 0, stream>>>(target, emb, xA);

  bf16* xin = xA;
  bf16* xout_ = xB;
  for (int l = 0; l < LAYERS; l++) {
    const float* eh_l = enc_hidden + (size_t)l * Bdim * Hdim;
    hinit<<<64, 256, 0, stream>>>(eh_l, hbfa, ctr);
    // xp = x @ W_ih[l]^T + b_ih[l]  : M=2048, N=3072, K=1024
    dim3 g1(BT / 128, G3H / 128);
    gemm_lds<true><<<g1, 256, 0, stream>>>(xin, wih_bf + (size_t)l * G3H * Hdim,
                                           b_ih + (size_t)l * G3H, xp, BT, G3H, Hdim);
    // all 32 GRU steps in one persistent launch
    gru_layer<<<256, 256, 0, stream>>>(hbfa, eh_l,
                                       whh_bf + (size_t)l * G3H * Hdim,
                                       b_hh + (size_t)l * G3H, xp,
                                       hbfa, hbfb, xout_,
                                       finals + (size_t)l * Bdim * Hdim, ctr);
    bf16* tmp = xin; xin = xout_; xout_ = tmp;
  }

  // logits = x @ W_out^T + b_out : M=2048, N=32000, K=1024 -> d_out
  dim3 g2(BT / 128, Vdim / 128);
  gemm_lds<true><<<g2, 256, 0, stream>>>(xin, wout_bf, b_out, out, BT, Vdim, Hdim);

  logsoftmax<<<BT, 256, 0, stream>>>(out);
}

// Round 3
// 1580.609 us; speedup vs baseline: 3.4774x; 3.4774x over previous
//
#include <hip/hip_runtime.h>
#include <hip/hip_bf16.h>
#include <cstdint>
#include <cstddef>

// Problem constants (match reference)
#define Hdim 1024
#define Vdim 32000
#define LAYERS 3
#define Bdim 64
#define Tdim 32
#define BT 2048      // B*T
#define G3H 3072     // 3*H

using bf16 = __bf16;
using bf16x8 = __attribute__((ext_vector_type(8))) __bf16;  // one MFMA A/B fragment (4 VGPRs)
using bf16x4 = __attribute__((ext_vector_type(4))) __bf16;
using f32x4  = __attribute__((ext_vector_type(4))) float;
using u32x4  = __attribute__((ext_vector_type(4))) unsigned int;

// async global->LDS, 16B per lane. LDS dest is wave-uniform base + lane*16.
typedef const __attribute__((address_space(1))) void* gas1_t;
typedef __attribute__((address_space(3))) void* las3_t;
__device__ __forceinline__ void g2lds16(const void* g, void* l) {
  __builtin_amdgcn_global_load_lds((gas1_t)g, (las3_t)l, 16, 0, 0);
}

// ---------------- fp32 -> bf16 conversion (weights) ----------------
__global__ __launch_bounds__(256) void cvt_f32_bf16(const float* __restrict__ src,
                                                    bf16* __restrict__ dst, int n4) {
  int i = blockIdx.x * 256 + threadIdx.x;
  if (i < n4) {
    f32x4 v = ((const f32x4*)src)[i];
    bf16x4 o;
    o[0] = (bf16)v[0]; o[1] = (bf16)v[1]; o[2] = (bf16)v[2]; o[3] = (bf16)v[3];
    ((bf16x4*)dst)[i] = o;
  }
}

// ---------------- embedding + relu -> bf16 x0 ----------------
__global__ __launch_bounds__(256) void embed_relu(const int* __restrict__ tgt,
                                                  const float* __restrict__ emb,
                                                  bf16* __restrict__ x) {
  int row = blockIdx.x;
  int b = row >> 5, t = row & 31;
  int id = (t == 0) ? 0 : tgt[b * Tdim + t - 1];
  const f32x4* src = (const f32x4*)(emb + (size_t)id * Hdim);
  bf16x4* dst = (bf16x4*)(x + (size_t)row * Hdim);
  f32x4 v = src[threadIdx.x];
  bf16x4 o;
  o[0] = (bf16)fmaxf(v[0], 0.f); o[1] = (bf16)fmaxf(v[1], 0.f);
  o[2] = (bf16)fmaxf(v[2], 0.f); o[3] = (bf16)fmaxf(v[3], 0.f);
  dst[threadIdx.x] = o;
}

// ---------------- hidden-state init: bf16 copy of encoder_hidden[l] + ctr reset ----
__global__ __launch_bounds__(256) void hinit(const float* __restrict__ eh,
                                             bf16* __restrict__ hbf,
                                             unsigned int* __restrict__ ctr) {
  if (blockIdx.x == 0 && threadIdx.x == 0) *ctr = 0u;
  int i = blockIdx.x * 256 + threadIdx.x;   // 64 blocks * 256 * 4 = 65536 floats
  f32x4 v = ((const f32x4*)eh)[i];
  bf16x4 o;
  o[0] = (bf16)v[0]; o[1] = (bf16)v[1]; o[2] = (bf16)v[2]; o[3] = (bf16)v[3];
  ((bf16x4*)hbf)[i] = o;
}

// ---------------- C = A @ B^T (+bias), LDS-staged (m97 structure) ----------------
// A: [M,K] bf16 row-major. Bm: [N,K] bf16 row-major. C: [M,N] fp32.
// Block 128x128 (4 waves, 64x64 each), BK=32, global_load_lds dwordx4 staging.
// XCD-chunked bijective swizzle (T1). Requires nwg % 8 == 0 (holds: 4000, 384).
template <bool BIAS>
__global__ __launch_bounds__(256) void gemm_lds(const bf16* __restrict__ A,
                                                const bf16* __restrict__ Bm,
                                                const float* __restrict__ bias,
                                                float* __restrict__ C,
                                                int M, int N, int K) {
  __shared__ bf16 As[128 * 32];   // 8 KB, row-major [128][32]
  __shared__ bf16 Bs[128 * 32];   // 8 KB

  int wave = threadIdx.x >> 6, lane = threadIdx.x & 63;
  int lane15 = lane & 15, quad = lane >> 4;
  int wr = wave >> 1, wc = wave & 1;

  int flat = blockIdx.y * gridDim.x + blockIdx.x;
  int per = (gridDim.x * gridDim.y) >> 3;
  int nid = (flat & 7) * per + (flat >> 3);
  int mt = nid % gridDim.x;
  int nt = nid / gridDim.x;
  int m0 = mt * 128;
  int n0 = nt * 128;

  int srow = wave * 16 + (lane >> 2);       // 0..63
  int scol = (lane & 3) * 8;                // 0,8,16,24
  const bf16* Asrc = A + (size_t)(m0 + srow) * K + scol;
  const bf16* Bsrc = Bm + (size_t)(n0 + srow) * K + scol;
  bf16* AdstW = As + (size_t)wave * 512;    // wave-uniform LDS base (elements)
  bf16* BdstW = Bs + (size_t)wave * 512;

  f32x4 acc[4][4] = {};
  for (int k0 = 0; k0 < K; k0 += 32) {
#pragma unroll
    for (int r = 0; r < 2; r++) {
      g2lds16(Asrc + (size_t)(r * 64) * K + k0, AdstW + r * 2048);
      g2lds16(Bsrc + (size_t)(r * 64) * K + k0, BdstW + r * 2048);
    }
    __syncthreads();

    bf16x8 a[4], b[4];
#pragma unroll
    for (int mi = 0; mi < 4; mi++)
      a[mi] = *(const bf16x8*)&As[(wr * 64 + mi * 16 + lane15) * 32 + quad * 8];
#pragma unroll
    for (int ni = 0; ni < 4; ni++)
      b[ni] = *(const bf16x8*)&Bs[(wc * 64 + ni * 16 + lane15) * 32 + quad * 8];
#pragma unroll
    for (int mi = 0; mi < 4; mi++)
#pragma unroll
      for (int ni = 0; ni < 4; ni++)
        acc[mi][ni] = __builtin_amdgcn_mfma_f32_16x16x32_bf16(a[mi], b[ni], acc[mi][ni], 0, 0, 0);
    __syncthreads();
  }

#pragma unroll
  for (int mi = 0; mi < 4; mi++)
#pragma unroll
    for (int ni = 0; ni < 4; ni++) {
      int col = n0 + wc * 64 + ni * 16 + lane15;
      float bv = BIAS ? bias[col] : 0.f;
#pragma unroll
      for (int r = 0; r < 4; r++) {
        int row = m0 + wr * 64 + mi * 16 + quad * 4 + r;
        C[(size_t)row * N + col] = acc[mi][ni][r] + bv;
      }
    }
}

// ---------------- persistent GRU layer: all 32 time steps in one launch ----------
// Grid = 256 blocks x 256 threads; 110 KB LDS forces exactly 1 block/CU, so all
// 256 blocks are co-resident (barrier is live). Block (i_tile=bid&63, b_tile=bid>>6)
// owns a 16b x 16i output patch; wave w owns K-slice [w*256, +256).
// Whh slice (3 gates x 16 rows x 1024) staged ONCE into LDS in fragment order.
// Cross-block h exchange: volatile (sc0 sc1, LLC-coherent) loads/stores ONLY for
// the h ping-pong buffers; NO threadfence (no L2 writeback/invalidate anywhere).
// Barrier: relaxed agent-scope atomic counter; __syncthreads() before arrival
// drains vmcnt(0) so write-through h stores are LLC-visible before the add.
__global__ __launch_bounds__(256, 1) void gru_layer(
    const float* __restrict__ eh,     // [B,H] fp32 initial h (encoder_hidden[l])
    const bf16* __restrict__ Whh,     // [3H,H] bf16
    const float* __restrict__ bhh,    // [3H]
    const float* __restrict__ xp,     // [BT,3H] fp32
    bf16* hbfa,                       // ping-pong bf16 h buffers (volatile access)
    bf16* hbfb,
    bf16* __restrict__ y,             // [BT,H] bf16 layer output
    float* __restrict__ finals,       // [B,H] fp32 final h for this layer
    unsigned int* ctr) {
  extern __shared__ uint8_t smem_raw[];
  bf16* Wl = (bf16*)smem_raw;                         // 98304 B: [wave][gate][j][lane][8]
  float* part = (float*)(smem_raw + 98304);           // 12288 B: [gate][wave][256]

  int tid = threadIdx.x;
  int wave = tid >> 6, lane = tid & 63;
  int lane15 = lane & 15, quad = lane >> 4;
  int bid = blockIdx.x;
  int i0 = (bid & 63) * 16;     // i-tile
  int b0 = (bid >> 6) * 16;     // b-tile
  int kbase = wave * 256;

  // ---- stage this block's Whh slice into LDS, fragment-ordered (once) ----
  {
    const bf16* Wb = Whh + (size_t)(i0 + lane15) * Hdim + kbase + quad * 8;
#pragma unroll
    for (int g = 0; g < 3; g++)
#pragma unroll
      for (int j = 0; j < 8; j++) {
        bf16x8 w = *(const bf16x8*)(Wb + (size_t)g * Hdim * Hdim + j * 32);
        *(bf16x8*)(Wl + ((((size_t)wave * 3 + g) * 8 + j) * 64 + lane) * 8) = w;
      }
  }

  // ---- per-output-thread constants ----
  int b_local = tid >> 4, i_local = tid & 15;
  int i_out = i0 + i_local;
  int b_out = b0 + b_local;
  float bhr = bhh[i_out], bhz = bhh[Hdim + i_out], bhn = bhh[2 * Hdim + i_out];
  size_t hi = (size_t)b_out * Hdim + i_out;
  float hold = eh[hi];                       // fp32 h carried in a register
  const float* xpr = xp + ((size_t)b_out * Tdim) * G3H;

  __syncthreads();   // Wl ready

  unsigned int target = 0;
  for (int t = 0; t < Tdim; t++) {
    const bf16* hp = (t & 1) ? hbfb : hbfa;
    bf16*       hn_ = (t & 1) ? hbfa : hbfb;

    // xp loads for this step (stable data, plain cached; issued early)
    float xr = xpr[(size_t)t * G3H + i_out];
    float xz = xpr[(size_t)t * G3H + Hdim + i_out];
    float xn = xpr[(size_t)t * G3H + 2 * Hdim + i_out];

    // h fragments: volatile (sc0 sc1) -> coherent at LLC, never stale
    const bf16* Ap = hp + (size_t)(b0 + lane15) * Hdim + kbase + quad * 8;
    bf16x8 a[8];
#pragma unroll
    for (int j = 0; j < 8; j++) {
      u32x4 raw = *(volatile const u32x4*)(Ap + j * 32);
      a[j] = __builtin_bit_cast(bf16x8, raw);
    }

    f32x4 ar = {}, az = {}, an = {};
#pragma unroll
    for (int j = 0; j < 8; j++) {
      const bf16* wbase = Wl + (((size_t)wave * 3) * 8 + j) * 64 * 8 + lane * 8;
      bf16x8 wr8 = *(const bf16x8*)(wbase);
      bf16x8 wz8 = *(const bf16x8*)(wbase + 8 * 64 * 8);
      bf16x8 wn8 = *(const bf16x8*)(wbase + 16 * 64 * 8);
      ar = __builtin_amdgcn_mfma_f32_16x16x32_bf16(a[j], wr8, ar, 0, 0, 0);
      az = __builtin_amdgcn_mfma_f32_16x16x32_bf16(a[j], wz8, az, 0, 0, 0);
      an = __builtin_amdgcn_mfma_f32_16x16x32_bf16(a[j], wn8, an, 0, 0, 0);
    }
    // C/D layout: row(m=b) = quad*4+r, col(n=i) = lane15
#pragma unroll
    for (int r = 0; r < 4; r++) {
      int idx = (quad * 4 + r) * 16 + lane15;
      part[(0 * 4 + wave) * 256 + idx] = ar[r];
      part[(1 * 4 + wave) * 256 + idx] = az[r];
      part[(2 * 4 + wave) * 256 + idx] = an[r];
    }
    __syncthreads();

    float hr = part[0 * 1024 + 0 * 256 + tid] + part[0 * 1024 + 1 * 256 + tid]
             + part[0 * 1024 + 2 * 256 + tid] + part[0 * 1024 + 3 * 256 + tid] + bhr;
    float hz = part[1 * 1024 + 0 * 256 + tid] + part[1 * 1024 + 1 * 256 + tid]
             + part[1 * 1024 + 2 * 256 + tid] + part[1 * 1024 + 3 * 256 + tid] + bhz;
    float hnp = part[2 * 1024 + 0 * 256 + tid] + part[2 * 1024 + 1 * 256 + tid]
              + part[2 * 1024 + 2 * 256 + tid] + part[2 * 1024 + 3 * 256 + tid] + bhn;
    float rg = 1.f / (1.f + __expf(-(xr + hr)));
    float zg = 1.f / (1.f + __expf(-(xz + hz)));
    float ng = tanhf(xn + rg * hnp);
    float hnew = (1.f - zg) * ng + zg * hold;
    hold = hnew;
    // h for next step: volatile write-through (visible at LLC once vmcnt retires)
    unsigned short us = __builtin_bit_cast(unsigned short, (bf16)hnew);
    ((volatile unsigned short*)hn_)[hi] = us;
    y[((size_t)b_out * Tdim + t) * Hdim + i_out] = (bf16)hnew;

    // ---- grid barrier: syncthreads (drains vmcnt) -> counter -> syncthreads ----
    __syncthreads();
    target += 256;
    if (tid == 0) {
      __hip_atomic_fetch_add(ctr, 1u, __ATOMIC_RELAXED, __HIP_MEMORY_SCOPE_AGENT);
      while (__hip_atomic_load(ctr, __ATOMIC_RELAXED, __HIP_MEMORY_SCOPE_AGENT) < target)
        __builtin_amdgcn_s_sleep(1);
    }
    __syncthreads();
  }
  finals[hi] = hold;
}

// ---------------- in-place log_softmax over V per row (float4) ----------------
__global__ __launch_bounds__(256) void logsoftmax(float* __restrict__ out) {
  __shared__ float sm[256], ss[256];
  int row = blockIdx.x;
  f32x4* x = (f32x4*)(out + (size_t)row * Vdim);
  const int n4 = Vdim / 4;  // 8000
  float m = -1e30f, s = 0.f;
  for (int j = threadIdx.x; j < n4; j += 256) {
    f32x4 v = x[j];
    float vm = fmaxf(fmaxf(v[0], v[1]), fmaxf(v[2], v[3]));
    float nm = fmaxf(m, vm);
    s = s * __expf(m - nm) + __expf(v[0] - nm) + __expf(v[1] - nm)
                           + __expf(v[2] - nm) + __expf(v[3] - nm);
    m = nm;
  }
  sm[threadIdx.x] = m; ss[threadIdx.x] = s;
  __syncthreads();
  for (int off = 128; off; off >>= 1) {
    if (threadIdx.x < off) {
      float m1 = sm[threadIdx.x], s1 = ss[threadIdx.x];
      float m2 = sm[threadIdx.x + off], s2 = ss[threadIdx.x + off];
      float mm = fmaxf(m1, m2);
      sm[threadIdx.x] = mm;
      ss[threadIdx.x] = s1 * __expf(m1 - mm) + s2 * __expf(m2 - mm);
    }
    __syncthreads();
  }
  float lse = sm[0] + logf(ss[0]);
  for (int j = threadIdx.x; j < n4; j += 256) {
    f32x4 v = x[j];
    v[0] -= lse; v[1] -= lse; v[2] -= lse; v[3] -= lse;
    x[j] = v;
  }
}

extern "C" void kernel_launch(void* const* d_in, const int* in_sizes, int n_in,
                              void* d_out, int out_size, void* d_ws, size_t ws_size,
                              hipStream_t stream) {
  const float* enc_hidden = (const float*)d_in[1];
  const int*   target     = (const int*)d_in[2];
  const float* emb        = (const float*)d_in[3];
  const float* W_ih       = (const float*)d_in[4];
  const float* W_hh       = (const float*)d_in[5];
  const float* b_ih       = (const float*)d_in[6];
  const float* b_hh       = (const float*)d_in[7];
  const float* W_out      = (const float*)d_in[8];
  const float* b_out      = (const float*)d_in[9];

  float* out = (float*)d_out;                       // [BT, V] logits/logprobs
  float* finals = out + (size_t)BT * Vdim;          // [L, B, H]

  uint8_t* wsp = (uint8_t*)d_ws;
  auto alloc = [&](size_t bytes) {
    uint8_t* p = wsp;
    wsp += (bytes + 255) & ~(size_t)255;
    return p;
  };
  bf16* wih_bf  = (bf16*)alloc((size_t)LAYERS * G3H * Hdim * 2);
  bf16* whh_bf  = (bf16*)alloc((size_t)LAYERS * G3H * Hdim * 2);
  bf16* wout_bf = (bf16*)alloc((size_t)Vdim * Hdim * 2);
  bf16* xA      = (bf16*)alloc((size_t)BT * Hdim * 2);
  bf16* xB      = (bf16*)alloc((size_t)BT * Hdim * 2);
  float* xp     = (float*)alloc((size_t)BT * G3H * 4);
  bf16* hbfa    = (bf16*)alloc((size_t)Bdim * Hdim * 2);
  bf16* hbfb    = (bf16*)alloc((size_t)Bdim * Hdim * 2);
  unsigned int* ctr = (unsigned int*)alloc(256);

  {
    int n4 = LAYERS * G3H * Hdim / 4;
    cvt_f32_bf16<<<(n4 + 255) / 256, 256, 0, stream>>>(W_ih, wih_bf, n4);
    cvt_f32_bf16<<<(n4 + 255) / 256, 256, 0, stream>>>(W_hh, whh_bf, n4);
    int m4 = Vdim * Hdim / 4;
    cvt_f32_bf16<<<(m4 + 255) / 256, 256, 0, stream>>>(W_out, wout_bf, m4);
  }

  embed_relu<<<BT, 256, 0, stream>>>(target, emb, xA);

  bf16* xin = xA;
  bf16* xout_ = xB;
  for (int l = 0; l < LAYERS; l++) {
    const float* eh_l = enc_hidden + (size_t)l * Bdim * Hdim;
    hinit<<<64, 256, 0, stream>>>(eh_l, hbfa, ctr);
    // xp = x @ W_ih[l]^T + b_ih[l]  : M=2048, N=3072, K=1024
    dim3 g1(BT / 128, G3H / 128);
    gemm_lds<true><<<g1, 256, 0, stream>>>(xin, wih_bf + (size_t)l * G3H * Hdim,
                                           b_ih + (size_t)l * G3H, xp, BT, G3H, Hdim);
    // all 32 GRU steps in one persistent launch (110592 B dynamic LDS)
    gru_layer<<<256, 256, 110592, stream>>>(eh_l,
                                            whh_bf + (size_t)l * G3H * Hdim,
                                            b_hh + (size_t)l * G3H, xp,
                                            hbfa, hbfb, xout_,
                                            finals + (size_t)l * Bdim * Hdim, ctr);
    bf16* tmp = xin; xin = xout_; xout_ = tmp;
  }

  // logits = x @ W_out^T + b_out : M=2048, N=32000, K=1024 -> d_out
  dim3 g2(BT / 128, Vdim / 128);
  gemm_lds<true><<<g2, 256, 0, stream>>>(xin, wout_bf, b_out, out, BT, Vdim, Hdim);

  logsoftmax<<<BT, 256, 0, stream>>>(out);
}

// Round 5
// 1407.234 us; speedup vs baseline: 3.9058x; 1.1232x over previous
//
#include <hip/hip_runtime.h>
#include <hip/hip_bf16.h>
#include <cstdint>
#include <cstddef>

// Problem constants (match reference)
#define Hdim 1024
#define Vdim 32000
#define LAYERS 3
#define Bdim 64
#define Tdim 32
#define BT 2048      // B*T
#define G3H 3072     // 3*H

using bf16 = __bf16;
using bf16x8 = __attribute__((ext_vector_type(8))) __bf16;  // one MFMA A/B fragment (4 VGPRs)
using bf16x4 = __attribute__((ext_vector_type(4))) __bf16;
using f32x4  = __attribute__((ext_vector_type(4))) float;
using u32x4  = __attribute__((ext_vector_type(4))) unsigned int;

// async global->LDS, 16B per lane. LDS dest is wave-uniform base + lane*16.
typedef const __attribute__((address_space(1))) void* gas1_t;
typedef __attribute__((address_space(3))) void* las3_t;
__device__ __forceinline__ void g2lds16(const void* g, void* l) {
  __builtin_amdgcn_global_load_lds((gas1_t)g, (las3_t)l, 16, 0, 0);
}

// ---------------- fp32 -> bf16 conversion (weights) ----------------
__global__ __launch_bounds__(256) void cvt_f32_bf16(const float* __restrict__ src,
                                                    bf16* __restrict__ dst, int n4) {
  int i = blockIdx.x * 256 + threadIdx.x;
  if (i < n4) {
    f32x4 v = ((const f32x4*)src)[i];
    bf16x4 o;
    o[0] = (bf16)v[0]; o[1] = (bf16)v[1]; o[2] = (bf16)v[2]; o[3] = (bf16)v[3];
    ((bf16x4*)dst)[i] = o;
  }
}

// ---------------- embedding + relu -> bf16 x0 ----------------
__global__ __launch_bounds__(256) void embed_relu(const int* __restrict__ tgt,
                                                  const float* __restrict__ emb,
                                                  bf16* __restrict__ x) {
  int row = blockIdx.x;
  int b = row >> 5, t = row & 31;
  int id = (t == 0) ? 0 : tgt[b * Tdim + t - 1];
  const f32x4* src = (const f32x4*)(emb + (size_t)id * Hdim);
  bf16x4* dst = (bf16x4*)(x + (size_t)row * Hdim);
  f32x4 v = src[threadIdx.x];
  bf16x4 o;
  o[0] = (bf16)fmaxf(v[0], 0.f); o[1] = (bf16)fmaxf(v[1], 0.f);
  o[2] = (bf16)fmaxf(v[2], 0.f); o[3] = (bf16)fmaxf(v[3], 0.f);
  dst[threadIdx.x] = o;
}

// ---------------- hidden-state init: bf16 copy of encoder_hidden[l] + ctr reset ----
__global__ __launch_bounds__(256) void hinit(const float* __restrict__ eh,
                                             bf16* __restrict__ hbf,
                                             unsigned int* __restrict__ ctr) {
  int i = blockIdx.x * 256 + threadIdx.x;
  if (i < 4096) ctr[i] = 0u;                // zero the whole barrier region (16 KB)
  f32x4 v = ((const f32x4*)eh)[i];
  bf16x4 o;
  o[0] = (bf16)v[0]; o[1] = (bf16)v[1]; o[2] = (bf16)v[2]; o[3] = (bf16)v[3];
  ((bf16x4*)hbf)[i] = o;
}

// ---------------- C = A @ B^T (+bias), LDS-staged (m97 structure) ----------------
// A: [M,K] bf16 row-major. Bm: [N,K] bf16 row-major. C: [M,N] fp32.
// Block 128x128 (4 waves, 64x64 each), BK=32, global_load_lds dwordx4 staging.
// XCD-chunked bijective swizzle (T1). Requires nwg % 8 == 0 (holds: 4000, 384).
// LDS slot-XOR swizzle (rule #21): global SOURCE slot is pre-swizzled with
// c ^= (row>>1)&3 so the linear global_load_lds write leaves logical slot c at
// LDS slot c^f(row); reads apply the same XOR -> quad's 16 lanes spread over
// all 8 bank-groups (2-way aliasing = free) instead of 8-way conflicts.
template <bool BIAS>
__global__ __launch_bounds__(256) void gemm_lds(const bf16* __restrict__ A,
                                                const bf16* __restrict__ Bm,
                                                const float* __restrict__ bias,
                                                float* __restrict__ C,
                                                int M, int N, int K) {
  __shared__ bf16 As[128 * 32];   // 8 KB, row-major [128][32], 16B slots XOR-swizzled
  __shared__ bf16 Bs[128 * 32];   // 8 KB

  int wave = threadIdx.x >> 6, lane = threadIdx.x & 63;
  int lane15 = lane & 15, quad = lane >> 4;
  int wr = wave >> 1, wc = wave & 1;

  int flat = blockIdx.y * gridDim.x + blockIdx.x;
  int per = (gridDim.x * gridDim.y) >> 3;
  int nid = (flat & 7) * per + (flat >> 3);
  int mt = nid % gridDim.x;
  int nt = nid / gridDim.x;
  int m0 = mt * 128;
  int n0 = nt * 128;

  // staging: lane l writes LDS row (wave*16 + l>>2), slot l&3 (linear dest).
  // source slot = (l&3) ^ f(row), f(row) = (row>>1)&3  (row+64 preserves f).
  int srow = wave * 16 + (lane >> 2);       // 0..63
  int scol = (((lane & 3) ^ ((srow >> 1) & 3)) * 8);
  const bf16* Asrc = A + (size_t)(m0 + srow) * K + scol;
  const bf16* Bsrc = Bm + (size_t)(n0 + srow) * K + scol;
  bf16* AdstW = As + (size_t)wave * 512;    // wave-uniform LDS base (elements)
  bf16* BdstW = Bs + (size_t)wave * 512;

  // read-side slot XOR: slot = quad ^ ((R>>1)&3); R's bits 1-2 come from lane15
  int rslot = (quad ^ ((lane15 >> 1) & 3)) * 8;

  f32x4 acc[4][4] = {};
  for (int k0 = 0; k0 < K; k0 += 32) {
#pragma unroll
    for (int r = 0; r < 2; r++) {
      g2lds16(Asrc + (size_t)(r * 64) * K + k0, AdstW + r * 2048);
      g2lds16(Bsrc + (size_t)(r * 64) * K + k0, BdstW + r * 2048);
    }
    __syncthreads();

    bf16x8 a[4], b[4];
#pragma unroll
    for (int mi = 0; mi < 4; mi++)
      a[mi] = *(const bf16x8*)&As[(wr * 64 + mi * 16 + lane15) * 32 + rslot];
#pragma unroll
    for (int ni = 0; ni < 4; ni++)
      b[ni] = *(const bf16x8*)&Bs[(wc * 64 + ni * 16 + lane15) * 32 + rslot];
#pragma unroll
    for (int mi = 0; mi < 4; mi++)
#pragma unroll
      for (int ni = 0; ni < 4; ni++)
        acc[mi][ni] = __builtin_amdgcn_mfma_f32_16x16x32_bf16(a[mi], b[ni], acc[mi][ni], 0, 0, 0);
    __syncthreads();
  }

#pragma unroll
  for (int mi = 0; mi < 4; mi++)
#pragma unroll
    for (int ni = 0; ni < 4; ni++) {
      int col = n0 + wc * 64 + ni * 16 + lane15;
      float bv = BIAS ? bias[col] : 0.f;
#pragma unroll
      for (int r = 0; r < 4; r++) {
        int row = m0 + wr * 64 + mi * 16 + quad * 4 + r;
        C[(size_t)row * N + col] = acc[mi][ni][r] + bv;
      }
    }
}

// ---------------- persistent GRU layer: all 32 time steps in one launch ----------
// Grid = 256 blocks x 256 threads; 110 KB LDS -> exactly 1 block/CU (co-resident).
// Block (i_tile=bid&63, b_tile=bid>>6) owns a 16b x 16i patch; wave w owns
// K-slice [w*256, +256). Whh slice staged ONCE into LDS in fragment order.
// h exchange: volatile (sc0 sc1, LLC-coherent) accesses; NO threadfence.
// Barrier: 4 INDEPENDENT per-b-tile-group barriers (batch rows independent),
// each two-level: 8 sub-counters (8 blocks each) -> group root; every counter
// on its own 256B line. Max serial RMWs per line = 8 (vs 256 before).
__global__ __launch_bounds__(256, 1) void gru_layer(
    const float* __restrict__ eh,     // [B,H] fp32 initial h (encoder_hidden[l])
    const bf16* __restrict__ Whh,     // [3H,H] bf16
    const float* __restrict__ bhh,    // [3H]
    const float* __restrict__ xp,     // [BT,3H] fp32
    bf16* hbfa,                       // ping-pong bf16 h buffers (volatile access)
    bf16* hbfb,
    bf16* __restrict__ y,             // [BT,H] bf16 layer output
    float* __restrict__ finals,       // [B,H] fp32 final h for this layer
    unsigned int* ctr) {
  extern __shared__ uint8_t smem_raw[];
  bf16* Wl = (bf16*)smem_raw;                         // 98304 B: [wave][gate][j][lane][8]
  float* part = (float*)(smem_raw + 98304);           // 12288 B: [gate][wave][256]

  int tid = threadIdx.x;
  int wave = tid >> 6, lane = tid & 63;
  int lane15 = lane & 15, quad = lane >> 4;
  int bid = blockIdx.x;
  int i0 = (bid & 63) * 16;     // i-tile
  int b0 = (bid >> 6) * 16;     // b-tile
  int kbase = wave * 256;

  // barrier addressing: group = b-tile (independent), sub = i-tile & 7
  int group = bid >> 6;
  unsigned int* subc  = ctr + (size_t)(group * 16 + (bid & 7)) * 64;
  unsigned int* rootc = ctr + (size_t)(group * 16 + 8) * 64;

  // ---- stage this block's Whh slice into LDS, fragment-ordered (once) ----
  {
    const bf16* Wb = Whh + (size_t)(i0 + lane15) * Hdim + kbase + quad * 8;
#pragma unroll
    for (int g = 0; g < 3; g++)
#pragma unroll
      for (int j = 0; j < 8; j++) {
        bf16x8 w = *(const bf16x8*)(Wb + (size_t)g * Hdim * Hdim + j * 32);
        *(bf16x8*)(Wl + ((((size_t)wave * 3 + g) * 8 + j) * 64 + lane) * 8) = w;
      }
  }

  // ---- per-output-thread constants ----
  int b_local = tid >> 4, i_local = tid & 15;
  int i_out = i0 + i_local;
  int b_out = b0 + b_local;
  float bhr = bhh[i_out], bhz = bhh[Hdim + i_out], bhn = bhh[2 * Hdim + i_out];
  size_t hi = (size_t)b_out * Hdim + i_out;
  float hold = eh[hi];                       // fp32 h carried in a register
  const float* xpr = xp + ((size_t)b_out * Tdim) * G3H;

  // xp prefetch for t=0
  float xr = xpr[i_out];
  float xz = xpr[Hdim + i_out];
  float xn = xpr[2 * Hdim + i_out];

  __syncthreads();   // Wl ready

  unsigned int roottarget = 0;
  for (int t = 0; t < Tdim; t++) {
    const bf16* hp = (t & 1) ? hbfb : hbfa;
    bf16*       hn_ = (t & 1) ? hbfa : hbfb;

    // h fragments: volatile (sc0 sc1) -> coherent at LLC, never stale
    const bf16* Ap = hp + (size_t)(b0 + lane15) * Hdim + kbase + quad * 8;
    bf16x8 a[8];
#pragma unroll
    for (int j = 0; j < 8; j++) {
      u32x4 raw = *(volatile const u32x4*)(Ap + j * 32);
      a[j] = __builtin_bit_cast(bf16x8, raw);
    }

    f32x4 ar = {}, az = {}, an = {};
#pragma unroll
    for (int j = 0; j < 8; j++) {
      const bf16* wbase = Wl + (((size_t)wave * 3) * 8 + j) * 64 * 8 + lane * 8;
      bf16x8 wr8 = *(const bf16x8*)(wbase);
      bf16x8 wz8 = *(const bf16x8*)(wbase + 8 * 64 * 8);
      bf16x8 wn8 = *(const bf16x8*)(wbase + 16 * 64 * 8);
      ar = __builtin_amdgcn_mfma_f32_16x16x32_bf16(a[j], wr8, ar, 0, 0, 0);
      az = __builtin_amdgcn_mfma_f32_16x16x32_bf16(a[j], wz8, az, 0, 0, 0);
      an = __builtin_amdgcn_mfma_f32_16x16x32_bf16(a[j], wn8, an, 0, 0, 0);
    }
    // C/D layout: row(m=b) = quad*4+r, col(n=i) = lane15
#pragma unroll
    for (int r = 0; r < 4; r++) {
      int idx = (quad * 4 + r) * 16 + lane15;
      part[(0 * 4 + wave) * 256 + idx] = ar[r];
      part[(1 * 4 + wave) * 256 + idx] = az[r];
      part[(2 * 4 + wave) * 256 + idx] = an[r];
    }

    // prefetch next step's xp (overlaps reduce + barrier latency)
    float xr2 = 0.f, xz2 = 0.f, xn2 = 0.f;
    if (t + 1 < Tdim) {
      xr2 = xpr[(size_t)(t + 1) * G3H + i_out];
      xz2 = xpr[(size_t)(t + 1) * G3H + Hdim + i_out];
      xn2 = xpr[(size_t)(t + 1) * G3H + 2 * Hdim + i_out];
    }
    __syncthreads();

    float hr = part[0 * 1024 + 0 * 256 + tid] + part[0 * 1024 + 1 * 256 + tid]
             + part[0 * 1024 + 2 * 256 + tid] + part[0 * 1024 + 3 * 256 + tid] + bhr;
    float hz = part[1 * 1024 + 0 * 256 + tid] + part[1 * 1024 + 1 * 256 + tid]
             + part[1 * 1024 + 2 * 256 + tid] + part[1 * 1024 + 3 * 256 + tid] + bhz;
    float hnp = part[2 * 1024 + 0 * 256 + tid] + part[2 * 1024 + 1 * 256 + tid]
              + part[2 * 1024 + 2 * 256 + tid] + part[2 * 1024 + 3 * 256 + tid] + bhn;
    float rg = 1.f / (1.f + __expf(-(xr + hr)));
    float zg = 1.f / (1.f + __expf(-(xz + hz)));
    float ng = tanhf(xn + rg * hnp);
    float hnew = (1.f - zg) * ng + zg * hold;
    hold = hnew;
    // h for next step: volatile write-through (visible at LLC once vmcnt retires)
    unsigned short us = __builtin_bit_cast(unsigned short, (bf16)hnew);
    ((volatile unsigned short*)hn_)[hi] = us;
    y[((size_t)b_out * Tdim + t) * Hdim + i_out] = (bf16)hnew;

    xr = xr2; xz = xz2; xn = xn2;

    // ---- group barrier: syncthreads (drains vmcnt) -> 2-level counter -> sync ----
    __syncthreads();
    roottarget += 8;
    if (tid == 0) {
      unsigned int old = __hip_atomic_fetch_add(subc, 1u, __ATOMIC_RELAXED,
                                                __HIP_MEMORY_SCOPE_AGENT);
      if ((old & 7) == 7)
        __hip_atomic_fetch_add(rootc, 1u, __ATOMIC_RELAXED, __HIP_MEMORY_SCOPE_AGENT);
      while (__hip_atomic_load(rootc, __ATOMIC_RELAXED, __HIP_MEMORY_SCOPE_AGENT) < roottarget)
        __builtin_amdgcn_s_sleep(1);
    }
    __syncthreads();
  }
  finals[hi] = hold;
}

// ---------------- in-place log_softmax over V per row (float4) ----------------
__global__ __launch_bounds__(256) void logsoftmax(float* __restrict__ out) {
  __shared__ float sm[256], ss[256];
  int row = blockIdx.x;
  f32x4* x = (f32x4*)(out + (size_t)row * Vdim);
  const int n4 = Vdim / 4;  // 8000
  float m = -1e30f, s = 0.f;
  for (int j = threadIdx.x; j < n4; j += 256) {
    f32x4 v = x[j];
    float vm = fmaxf(fmaxf(v[0], v[1]), fmaxf(v[2], v[3]));
    float nm = fmaxf(m, vm);
    s = s * __expf(m - nm) + __expf(v[0] - nm) + __expf(v[1] - nm)
                           + __expf(v[2] - nm) + __expf(v[3] - nm);
    m = nm;
  }
  sm[threadIdx.x] = m; ss[threadIdx.x] = s;
  __syncthreads();
  for (int off = 128; off; off >>= 1) {
    if (threadIdx.x < off) {
      float m1 = sm[threadIdx.x], s1 = ss[threadIdx.x];
      float m2 = sm[threadIdx.x + off], s2 = ss[threadIdx.x + off];
      float mm = fmaxf(m1, m2);
      sm[threadIdx.x] = mm;
      ss[threadIdx.x] = s1 * __expf(m1 - mm) + s2 * __expf(m2 - mm);
    }
    __syncthreads();
  }
  float lse = sm[0] + logf(ss[0]);
  for (int j = threadIdx.x; j < n4; j += 256) {
    f32x4 v = x[j];
    v[0] -= lse; v[1] -= lse; v[2] -= lse; v[3] -= lse;
    x[j] = v;
  }
}

extern "C" void kernel_launch(void* const* d_in, const int* in_sizes, int n_in,
                              void* d_out, int out_size, void* d_ws, size_t ws_size,
                              hipStream_t stream) {
  const float* enc_hidden = (const float*)d_in[1];
  const int*   target     = (const int*)d_in[2];
  const float* emb        = (const float*)d_in[3];
  const float* W_ih       = (const float*)d_in[4];
  const float* W_hh       = (const float*)d_in[5];
  const float* b_ih       = (const float*)d_in[6];
  const float* b_hh       = (const float*)d_in[7];
  const float* W_out      = (const float*)d_in[8];
  const float* b_out      = (const float*)d_in[9];

  float* out = (float*)d_out;                       // [BT, V] logits/logprobs
  float* finals = out + (size_t)BT * Vdim;          // [L, B, H]

  uint8_t* wsp = (uint8_t*)d_ws;
  auto alloc = [&](size_t bytes) {
    uint8_t* p = wsp;
    wsp += (bytes + 255) & ~(size_t)255;
    return p;
  };
  bf16* wih_bf  = (bf16*)alloc((size_t)LAYERS * G3H * Hdim * 2);
  bf16* whh_bf  = (bf16*)alloc((size_t)LAYERS * G3H * Hdim * 2);
  bf16* wout_bf = (bf16*)alloc((size_t)Vdim * Hdim * 2);
  bf16* xA      = (bf16*)alloc((size_t)BT * Hdim * 2);
  bf16* xB      = (bf16*)alloc((size_t)BT * Hdim * 2);
  float* xp     = (float*)alloc((size_t)BT * G3H * 4);
  bf16* hbfa    = (bf16*)alloc((size_t)Bdim * Hdim * 2);
  bf16* hbfb    = (bf16*)alloc((size_t)Bdim * Hdim * 2);
  unsigned int* ctr = (unsigned int*)alloc(16384);  // 4 groups x 16 lines x 256B

  {
    int n4 = LAYERS * G3H * Hdim / 4;
    cvt_f32_bf16<<<(n4 + 255) / 256, 256, 0, stream>>>(W_ih, wih_bf, n4);
    cvt_f32_bf16<<<(n4 + 255) / 256, 256, 0, stream>>>(W_hh, whh_bf, n4);
    int m4 = Vdim * Hdim / 4;
    cvt_f32_bf16<<<(m4 + 255) / 256, 256, 0, stream>>>(W_out, wout_bf, m4);
  }

  embed_relu<<<BT, 256, 0, stream>>>(target, emb, xA);

  bf16* xin = xA;
  bf16* xout_ = xB;
  for (int l = 0; l < LAYERS; l++) {
    const float* eh_l = enc_hidden + (size_t)l * Bdim * Hdim;
    hinit<<<64, 256, 0, stream>>>(eh_l, hbfa, ctr);
    // xp = x @ W_ih[l]^T + b_ih[l]  : M=2048, N=3072, K=1024
    dim3 g1(BT / 128, G3H / 128);
    gemm_lds<true><<<g1, 256, 0, stream>>>(xin, wih_bf + (size_t)l * G3H * Hdim,
                                           b_ih + (size_t)l * G3H, xp, BT, G3H, Hdim);
    // all 32 GRU steps in one persistent launch (110592 B dynamic LDS)
    gru_layer<<<256, 256, 110592, stream>>>(eh_l,
                                            whh_bf + (size_t)l * G3H * Hdim,
                                            b_hh + (size_t)l * G3H, xp,
                                            hbfa, hbfb, xout_,
                                            finals + (size_t)l * Bdim * Hdim, ctr);
    bf16* tmp = xin; xin = xout_; xout_ = tmp;
  }

  // logits = x @ W_out^T + b_out : M=2048, N=32000, K=1024 -> d_out
  dim3 g2(BT / 128, Vdim / 128);
  gemm_lds<true><<<g2, 256, 0, stream>>>(xin, wout_bf, b_out, out, BT, Vdim, Hdim);

  logsoftmax<<<BT, 256, 0, stream>>>(out);
}